// Round 8
// baseline (376.277 us; speedup 1.0000x reference)
//
#include <hip/hip_runtime.h>
#include <hip/hip_bf16.h>
#include <math.h>

#define NTRI 69
#define NB 128
#define IN_LEN 864
#define MS_LEN 39744
#define W_CPLX 953856      // 24*MS_LEN
#define EPSV 1e-5f

typedef short short8 __attribute__((ext_vector_type(8)));
typedef float f32x4 __attribute__((ext_vector_type(4)));
typedef __hip_bfloat16 bf16;

// ---- compile-time triple tables ----
struct Tables { int l1[NTRI], l2[NTRI], lo[NTRI], tpos[NTRI], cgoff[NTRI], ncg; };
constexpr Tables make_tables(){
  Tables t{};
  int cnt[6]={0,0,0,0,0,0}; int n=0, ncg=0;
  for(int a=0;a<=5;++a)
    for(int b=0;b<=a;++b)
      for(int l=a-b; l<=((a+b<5)?(a+b):5); ++l){
        t.l1[n]=a; t.l2[n]=b; t.lo[n]=l; t.tpos[n]=cnt[l]++;
        t.cgoff[n]=ncg; ncg+=(2*l+1)*(2*a+1); ++n;
      }
  t.ncg=ncg; return t;
}
constexpr Tables TB = make_tables();
constexpr int MT[6]   = {3456,5760,7488,8064,8064,6912};
constexpr int MSOFF[7]= {0,3456,9216,16704,24768,32832,39744};

struct MPar {
  int bb[NTRI];                 // B column base (elements): boff[l]+tpos*1152 (interleaved K)
  int gch[NTRI];                // global middle-channel base
  unsigned char otri[NTRI];     // heavy-first block order
};
struct CMeta { unsigned char l1[NTRI], l2[NTRI], lo[NTRI]; int cg_off[NTRI]; };
struct GMeta { int aoff[6], boff[6], K[6], mt[6], w_off[6], ms_off[7], tb[7]; };

__constant__ double c_fac[18] = {
  1.0,1.0,2.0,6.0,24.0,120.0,720.0,5040.0,40320.0,362880.0,3628800.0,
  39916800.0,479001600.0,6227020800.0,87178291200.0,1307674368000.0,
  20922789888000.0,355687428096000.0 };

__device__ double cg_coef(int j1,int m1,int j2,int m2,int j,int m){
  if (m1+m2!=m) return 0.0;
  double pref = sqrt((2.0*j+1.0)*c_fac[j+j1-j2]*c_fac[j-j1+j2]*c_fac[j1+j2-j]/c_fac[j1+j2+j+1]);
  pref *= sqrt(c_fac[j+m]*c_fac[j-m]*c_fac[j1-m1]*c_fac[j1+m1]*c_fac[j2-m2]*c_fac[j2+m2]);
  int kmin = max(0, max(-(j-j2+m1), -(j-j1-m2)));
  int kmax = min(j1+j2-j, min(j1-m1, j2+m2));
  double s = 0.0;
  for (int k=kmin;k<=kmax;++k){
    double d = c_fac[k]*c_fac[j1+j2-j-k]*c_fac[j1-m1-k]*c_fac[j2+m2-k]*c_fac[j-j2+m1+k]*c_fac[j-j1-m2+k];
    s += ((k&1)? -1.0:1.0)/d;
  }
  return pref*s;
}

__global__ void k_init_cg(float* __restrict__ cg, CMeta cm){
  int tri = blockIdx.x;
  int l1=cm.l1[tri], l2=cm.l2[tri], l=cm.lo[tri];
  int n1=2*l1+1, nm=2*l+1;
  int n=nm*n1;
  for (int e=threadIdx.x; e<n; e+=blockDim.x){
    int mi=e/n1, xi=e-mi*n1;
    int m=mi-l, m1=xi-l1, m2=m-m1;
    float v=0.f;
    if (m2>=-l2 && m2<=l2) v=(float)cg_coef(l1,m1,l2,m2,l,m);
    cg[cm.cg_off[tri]+e]=v;
  }
}

// ---- per-TRIPLE middle kernel: 192 threads, 3 adjacent channels per thread,
//      1 batch per block-row. ts0=3*tid -> same t for all 3 channels. ----
template<int TRI>
__device__ __forceinline__ void mid_body(
    const float2* __restrict__ act, const float* __restrict__ cg,
    bf16* __restrict__ Bm, float* __restrict__ partial,
    const MPar& mp, int b0, float* cgl)
{
  constexpr int L1=TB.l1[TRI], L2=TB.l2[TRI], L=TB.lo[TRI];
  constexpr int N1=2*L1+1, N2=2*L2+1, NM=2*L+1;
  constexpr int D=L1+L2-L;
  constexpr int MTL=MT[L], KL=2*MTL;
  for (int i=threadIdx.x; i<NM*N1; i+=192) cgl[i]=cg[TB.cgoff[TRI]+i];
  __syncthreads();
  const int tid=threadIdx.x;
  const int t=tid>>3;                 // = (3*tid)/24
  const int s0=3*(tid&7);
  const int ts0=3*tid;
  const int a1=24*L1*L1+t*N1, a2=24*L2*L2+s0*N2;
  const int brel=(int)blockIdx.y;
  const int b=b0+brel;
  const float2* ab=act+(size_t)b*IN_LEN;
  float f1r[N1],f1i[N1];
  #pragma unroll
  for (int x=0;x<N1;++x){ float2 v=ab[a1+x]; f1r[x]=v.x; f1i[x]=v.y; }
  float f2r[3][N2], f2i[3][N2];
  #pragma unroll
  for (int j=0;j<3;++j)
    #pragma unroll
    for (int y=0;y<N2;++y){ float2 v=ab[a2+j*N2+y]; f2r[j][y]=v.x; f2i[j][y]=v.y; }
  float ss0=0.f, ss1=0.f, ss2=0.f;
  const size_t rowb=(size_t)mp.bb[TRI]+(size_t)brel*NM*KL+2*ts0;
  #pragma unroll
  for (int m=0;m<NM;++m){
    float fr0=0.f,fi0=0.f,fr1=0.f,fi1=0.f,fr2=0.f,fi2=0.f;
    #pragma unroll
    for (int x=0;x<N1;++x){
      const int y=m-x+D;
      if (y>=0 && y<N2){
        float cv=cgl[m*N1+x];
        float ar=cv*f1r[x], ai=cv*f1i[x];
        fr0 += ar*f2r[0][y]-ai*f2i[0][y];  fi0 += ar*f2i[0][y]+ai*f2r[0][y];
        fr1 += ar*f2r[1][y]-ai*f2i[1][y];  fi1 += ar*f2i[1][y]+ai*f2r[1][y];
        fr2 += ar*f2r[2][y]-ai*f2i[2][y];  fi2 += ar*f2i[2][y]+ai*f2r[2][y];
      }
    }
    ss0 += fr0*fr0+fi0*fi0;  ss1 += fr1*fr1+fi1*fi1;  ss2 += fr2*fr2+fi2*fi2;
    union { bf16 h[2]; unsigned u; } p0,p1,p2;
    p0.h[0]=__float2bfloat16(fr0); p0.h[1]=__float2bfloat16(fi0);
    p1.h[0]=__float2bfloat16(fr1); p1.h[1]=__float2bfloat16(fi1);
    p2.h[0]=__float2bfloat16(fr2); p2.h[1]=__float2bfloat16(fi2);
    unsigned* dst=reinterpret_cast<unsigned*>(Bm+rowb+(size_t)m*KL);
    dst[0]=p0.u; dst[1]=p1.u; dst[2]=p2.u;
  }
  float* pp = partial + (size_t)b*MS_LEN + mp.gch[TRI] + ts0;
  pp[0]=ss0; pp[1]=ss1; pp[2]=ss2;
}

__global__ __launch_bounds__(192,4)
void k_mid3(const float2* __restrict__ act, const float* __restrict__ cg,
            bf16* __restrict__ Bm, float* __restrict__ partial, MPar mp, int b0){
  __shared__ float cgl[121];
  int tri = mp.otri[blockIdx.x];
  #define CASE(T) case T: mid_body<T>(act,cg,Bm,partial,mp,b0,cgl); break;
  switch(tri){
    CASE(0) CASE(1) CASE(2) CASE(3) CASE(4) CASE(5) CASE(6) CASE(7) CASE(8)
    CASE(9) CASE(10) CASE(11) CASE(12) CASE(13) CASE(14) CASE(15) CASE(16)
    CASE(17) CASE(18) CASE(19) CASE(20) CASE(21) CASE(22) CASE(23) CASE(24)
    CASE(25) CASE(26) CASE(27) CASE(28) CASE(29) CASE(30) CASE(31) CASE(32)
    CASE(33) CASE(34) CASE(35) CASE(36) CASE(37) CASE(38) CASE(39) CASE(40)
    CASE(41) CASE(42) CASE(43) CASE(44) CASE(45) CASE(46) CASE(47) CASE(48)
    CASE(49) CASE(50) CASE(51) CASE(52) CASE(53) CASE(54) CASE(55) CASE(56)
    CASE(57) CASE(58) CASE(59) CASE(60) CASE(61) CASE(62) CASE(63) CASE(64)
    CASE(65) CASE(66) CASE(67) CASE(68)
    default: break;
  }
  #undef CASE
}

__global__ __launch_bounds__(256)
void k_scale(const float* __restrict__ partial, const float* __restrict__ mstd,
             float* __restrict__ scale, GMeta gm){
  int c=blockIdx.x*256+threadIdx.x;
  if (c>=MS_LEN) return;
  int l=0;
  #pragma unroll
  for (int i=1;i<6;++i) if (c>=gm.ms_off[i]) l=i;
  float ss=0.f;
  for (int g=0;g<NB;++g) ss += partial[(size_t)g*MS_LEN+c];
  float bstd = sqrtf(ss/(128.f*(float)(2*l+1)));
  scale[c] = 1.f/(0.5f*(mstd[c]+bstd)+EPSV);
}

// A with re/im-interleaved K to match B: col 2c = re-part, col 2c+1 = im-part
__global__ __launch_bounds__(256)
void k_buildA(const float2* __restrict__ wts, const float* __restrict__ scale,
              bf16* __restrict__ Am, GMeta gm){
  int i=blockIdx.x*256+threadIdx.x;
  if (i>=W_CPLX) return;
  int l=0;
  #pragma unroll
  for (int j=1;j<6;++j) if (i>=gm.w_off[j]) l=j;
  int j=i-gm.w_off[l];
  int mt=gm.mt[l];
  int o=j/mt, c=j-o*mt;
  float2 w=wts[i];
  float s=scale[gm.ms_off[l]+c];
  size_t K=(size_t)gm.K[l];
  bf16* Al=Am+gm.aoff[l];
  union { bf16 h[2]; unsigned u; } p0, p1;
  p0.h[0]=__float2bfloat16(w.x*s);  p0.h[1]=__float2bfloat16(-w.y*s);
  p1.h[0]=__float2bfloat16(w.y*s);  p1.h[1]=__float2bfloat16(w.x*s);
  *reinterpret_cast<unsigned*>(Al+(size_t)o*K+2*c)      = p0.u;
  *reinterpret_cast<unsigned*>(Al+(size_t)(24+o)*K+2*c) = p1.u;
}

// GEMM with K split over blockIdx.y into 4 chunks; per-chunk 48x16 tile -> part
__global__ __launch_bounds__(256)
void k_gemm2(const bf16* __restrict__ Am, const bf16* __restrict__ Bm,
             float* __restrict__ part, GMeta gm){
  int bid=blockIdx.x, z=blockIdx.y;
  int l=0;
  #pragma unroll
  for (int i=1;i<6;++i) if (bid>=gm.tb[i]) l=i;
  int ntile=bid-gm.tb[l];
  int K=gm.K[l];
  int tid=threadIdx.x, lane=tid&63, w=tid>>6;
  int r=lane&15, kg=lane>>4;
  int nit=K>>7;
  int nz=(nit+3)>>2;
  int it0=z*nz, it1=(nit<it0+nz)?nit:(it0+nz);
  f32x4 acc0={0.f,0.f,0.f,0.f}, acc1=acc0, acc2=acc0;
  __shared__ float red[3072];
  if (it0<it1){
    const bf16* Al=Am+gm.aoff[l];
    const bf16* Bl=Bm+gm.boff[l];
    size_t koff=(size_t)(w*32+kg*8)+(size_t)it0*128;
    const short8* pa0=(const short8*)(Al+(size_t)r*K+koff);
    const short8* pa1=(const short8*)(Al+(size_t)(16+r)*K+koff);
    const short8* pa2=(const short8*)(Al+(size_t)(32+r)*K+koff);
    const short8* pb =(const short8*)(Bl+(size_t)(ntile*16+r)*K+koff);
    short8 ca0=*pa0, ca1=*pa1, ca2=*pa2, cb=*pb;
    for (int it=it0+1; it<it1; ++it){
      pa0+=16; pa1+=16; pa2+=16; pb+=16;
      short8 na0=*pa0, na1=*pa1, na2=*pa2, nb_=*pb;
      acc0=__builtin_amdgcn_mfma_f32_16x16x32_bf16(ca0,cb,acc0,0,0,0);
      acc1=__builtin_amdgcn_mfma_f32_16x16x32_bf16(ca1,cb,acc1,0,0,0);
      acc2=__builtin_amdgcn_mfma_f32_16x16x32_bf16(ca2,cb,acc2,0,0,0);
      ca0=na0; ca1=na1; ca2=na2; cb=nb_;
    }
    acc0=__builtin_amdgcn_mfma_f32_16x16x32_bf16(ca0,cb,acc0,0,0,0);
    acc1=__builtin_amdgcn_mfma_f32_16x16x32_bf16(ca1,cb,acc1,0,0,0);
    acc2=__builtin_amdgcn_mfma_f32_16x16x32_bf16(ca2,cb,acc2,0,0,0);
  }
  #pragma unroll
  for (int reg=0;reg<4;++reg){
    int row0=kg*4+reg;
    red[(w*48+row0)*16+r]     =acc0[reg];
    red[(w*48+16+row0)*16+r]  =acc1[reg];
    red[(w*48+32+row0)*16+r]  =acc2[reg];
  }
  __syncthreads();
  float* po = part + (size_t)(bid*4+z)*768;
  for (int e=tid;e<768;e+=256)
    po[e]=red[e]+red[768+e]+red[1536+e]+red[2304+e];
}

__global__ __launch_bounds__(256)
void k_red(const float* __restrict__ part, float* __restrict__ outf,
           GMeta gm, int b0){
  int bid=blockIdx.x;
  int l=0;
  #pragma unroll
  for (int i=1;i<6;++i) if (bid>=gm.tb[i]) l=i;
  int ntile=bid-gm.tb[l];
  int nm=2*l+1;
  const float* po = part + (size_t)bid*4*768;
  for (int e=threadIdx.x;e<768;e+=256){
    float sv=po[e]+po[768+e]+po[1536+e]+po[2304+e];
    int o=e>>4, cc=e&15;
    int n=ntile*16+cc;
    int bb=n/nm, m=n-bb*nm;
    int b=b0+bb;
    int oo=(o<24)?o:(o-24);
    int comp=(o<24)?0:1;
    outf[((size_t)b*IN_LEN + 24*l*l + oo*nm + m)*2 + comp]=sv;
  }
}

extern "C" void kernel_launch(void* const* d_in, const int* in_sizes, int n_in,
                              void* d_out, int out_size, void* d_ws, size_t ws_size,
                              hipStream_t stream) {
  const float2* act  = (const float2*)d_in[0];
  const float2* wts  = (const float2*)d_in[1];
  const float*  mstd = (const float*)d_in[2];
  float* outf = (float*)d_out;
  (void)in_sizes; (void)n_in; (void)out_size;

  GMeta gm; CMeta cm; MPar mp;
  for (int l=0;l<6;++l){ gm.mt[l]=MT[l]; gm.K[l]=2*MT[l]; }
  for (int l=0;l<7;++l) gm.ms_off[l]=MSOFF[l];
  for (int l=0;l<6;++l) gm.w_off[l]=24*gm.ms_off[l];
  int atot=0;
  for (int l=0;l<6;++l){ gm.aoff[l]=atot; atot+=48*gm.K[l]; }
  for (int i=0;i<NTRI;++i){
    cm.l1[i]=(unsigned char)TB.l1[i]; cm.l2[i]=(unsigned char)TB.l2[i];
    cm.lo[i]=(unsigned char)TB.lo[i]; cm.cg_off[i]=TB.cgoff[i];
    mp.gch[i]=MSOFF[TB.lo[i]]+TB.tpos[i]*576;
  }
  int ncg=TB.ncg;

  // heavy-first block order
  {
    int ordt[NTRI];
    for (int i=0;i<NTRI;++i) ordt[i]=i;
    for (int i=1;i<NTRI;++i){
      int v=ordt[i];
      int wv=(2*TB.lo[v]+1)*(2*TB.l1[v]+1);
      int j=i-1;
      while (j>=0){
        int wj=(2*TB.lo[ordt[j]]+1)*(2*TB.l1[ordt[j]]+1);
        if (wj>=wv) break;
        ordt[j+1]=ordt[j]; --j;
      }
      ordt[j+1]=v;
    }
    for (int i=0;i<NTRI;++i) mp.otri[i]=(unsigned char)ordt[i];
  }

  // ---- ws layout ----
  size_t ob=0;
  auto alloc=[&](size_t bytes){ size_t o=ob; ob=(ob+bytes+255)&~255ULL; return o; };
  size_t off_cg      = alloc((size_t)ncg*4);
  size_t off_scale   = alloc((size_t)MS_LEN*4);
  size_t off_partial = alloc((size_t)NB*MS_LEN*4);
  size_t off_A       = alloc((size_t)atot*2);
  size_t off_part    = alloc((size_t)288*4*768*4);
  size_t off_B       = ob;

  size_t perB=0;
  for (int l=0;l<6;++l) perB += (size_t)(2*l+1)*gm.K[l]*2;
  int nb=16;
  for (int cand : {128,64,32,16})
    if (off_B + (size_t)cand*perB <= ws_size){ nb=cand; break; }

  { int bo=0; for (int l=0;l<6;++l){ gm.boff[l]=bo; bo+=nb*(2*l+1)*gm.K[l]; } }
  gm.tb[0]=0;
  for (int l=0;l<6;++l) gm.tb[l+1]=gm.tb[l]+nb*(2*l+1)/16;
  for (int i=0;i<NTRI;++i)
    mp.bb[i] = gm.boff[TB.lo[i]] + TB.tpos[i]*1152;   // column base, interleaved K

  uint8_t* wsb=(uint8_t*)d_ws;
  float* cg      =(float*)(wsb+off_cg);
  float* scale   =(float*)(wsb+off_scale);
  float* partial =(float*)(wsb+off_partial);
  bf16*  Am      =(bf16*)(wsb+off_A);
  float* part    =(float*)(wsb+off_part);
  bf16*  Bm      =(bf16*)(wsb+off_B);

  k_init_cg<<<NTRI,64,0,stream>>>(cg, cm);
  int tiles=gm.tb[6];
  if (nb==NB){
    k_mid3<<<dim3(NTRI,NB),192,0,stream>>>(act,cg,Bm,partial,mp,0);
    k_scale<<<(MS_LEN+255)/256,256,0,stream>>>(partial,mstd,scale,gm);
    k_buildA<<<(W_CPLX+255)/256,256,0,stream>>>(wts,scale,Am,gm);
    k_gemm2<<<dim3(tiles,4),256,0,stream>>>(Am,Bm,part,gm);
    k_red<<<tiles,256,0,stream>>>(part,outf,gm,0);
  } else {
    for (int b0=0;b0<NB;b0+=nb)
      k_mid3<<<dim3(NTRI,nb),192,0,stream>>>(act,cg,Bm,partial,mp,b0);
    k_scale<<<(MS_LEN+255)/256,256,0,stream>>>(partial,mstd,scale,gm);
    k_buildA<<<(W_CPLX+255)/256,256,0,stream>>>(wts,scale,Am,gm);
    for (int b0=0;b0<NB;b0+=nb){
      k_mid3<<<dim3(NTRI,nb),192,0,stream>>>(act,cg,Bm,partial,mp,b0);
      k_gemm2<<<dim3(tiles,4),256,0,stream>>>(Am,Bm,part,gm);
      k_red<<<tiles,256,0,stream>>>(part,outf,gm,b0);
    }
  }
}

// Round 9
// 162.059 us; speedup vs baseline: 2.3219x; 2.3219x over previous
//
#include <hip/hip_runtime.h>
#include <hip/hip_bf16.h>
#include <math.h>

#define NTRI 69
#define NB 128
#define IN_LEN 864
#define MS_LEN 39744
#define EPSV 1e-5f

typedef short short8 __attribute__((ext_vector_type(8)));
typedef float f32x4 __attribute__((ext_vector_type(4)));
typedef __hip_bfloat16 bf16;

// ---- compile-time triple tables ----
struct Tables { int l1[NTRI], l2[NTRI], lo[NTRI], tpos[NTRI], cgoff[NTRI], ncg; };
constexpr Tables make_tables(){
  Tables t{};
  int cnt[6]={0,0,0,0,0,0}; int n=0, ncg=0;
  for(int a=0;a<=5;++a)
    for(int b=0;b<=a;++b)
      for(int l=a-b; l<=((a+b<5)?(a+b):5); ++l){
        t.l1[n]=a; t.l2[n]=b; t.lo[n]=l; t.tpos[n]=cnt[l]++;
        t.cgoff[n]=ncg; ncg+=(2*l+1)*(2*a+1); ++n;
      }
  t.ncg=ncg; return t;
}
constexpr Tables TB = make_tables();
constexpr int MT[6]   = {3456,5760,7488,8064,8064,6912};
constexpr int MSOFF[7]= {0,3456,9216,16704,24768,32832,39744};

struct MPar {
  int bb[NTRI];                 // B column base (elements): boff[l]+tpos*1152 (interleaved K)
  int gch[NTRI];                // global middle-channel base
  unsigned char otri[NTRI];     // heavy-first block order
};
struct CMeta { unsigned char l1[NTRI], l2[NTRI], lo[NTRI]; int cg_off[NTRI]; };
struct GMeta { int aoff[6], boff[6], K[6], mt[6], w_off[6], ms_off[7], tb[7]; };

__constant__ double c_fac[18] = {
  1.0,1.0,2.0,6.0,24.0,120.0,720.0,5040.0,40320.0,362880.0,3628800.0,
  39916800.0,479001600.0,6227020800.0,87178291200.0,1307674368000.0,
  20922789888000.0,355687428096000.0 };

__device__ double cg_coef(int j1,int m1,int j2,int m2,int j,int m){
  if (m1+m2!=m) return 0.0;
  double pref = sqrt((2.0*j+1.0)*c_fac[j+j1-j2]*c_fac[j-j1+j2]*c_fac[j1+j2-j]/c_fac[j1+j2+j+1]);
  pref *= sqrt(c_fac[j+m]*c_fac[j-m]*c_fac[j1-m1]*c_fac[j1+m1]*c_fac[j2-m2]*c_fac[j2+m2]);
  int kmin = max(0, max(-(j-j2+m1), -(j-j1-m2)));
  int kmax = min(j1+j2-j, min(j1-m1, j2+m2));
  double s = 0.0;
  for (int k=kmin;k<=kmax;++k){
    double d = c_fac[k]*c_fac[j1+j2-j-k]*c_fac[j1-m1-k]*c_fac[j2+m2-k]*c_fac[j-j2+m1+k]*c_fac[j-j1-m2+k];
    s += ((k&1)? -1.0:1.0)/d;
  }
  return pref*s;
}

__global__ void k_init_cg(float* __restrict__ cg, CMeta cm){
  int tri = blockIdx.x;
  int l1=cm.l1[tri], l2=cm.l2[tri], l=cm.lo[tri];
  int n1=2*l1+1, nm=2*l+1;
  int n=nm*n1;
  for (int e=threadIdx.x; e<n; e+=blockDim.x){
    int mi=e/n1, xi=e-mi*n1;
    int m=mi-l, m1=xi-l1, m2=m-m1;
    float v=0.f;
    if (m2>=-l2 && m2<=l2) v=(float)cg_coef(l1,m1,l2,m2,l,m);
    cg[cm.cg_off[tri]+e]=v;
  }
}

// ---- per-TRIPLE middle kernel (R6 structure, LDS-staged act row) ----
// one thread = (channel, 1 batch); store pattern byte-identical to round 6.
template<int TRI>
__device__ __forceinline__ void mid_body(
    const float2* __restrict__ act, const float* __restrict__ cg,
    bf16* __restrict__ Bm, float* __restrict__ partial,
    const MPar& mp, int ts, int b0, float* cgl, float2* s_act)
{
  constexpr int L1=TB.l1[TRI], L2=TB.l2[TRI], L=TB.lo[TRI];
  constexpr int N1=2*L1+1, N2=2*L2+1, NM=2*L+1;
  constexpr int D=L1+L2-L;
  constexpr int MTL=MT[L], KL=2*MTL;
  const int brel=(int)blockIdx.y;
  const int b=b0+brel;
  // stage CG table + this batch's full act row into LDS (coalesced float4)
  for (int i=threadIdx.x; i<NM*N1; i+=192) cgl[i]=cg[TB.cgoff[TRI]+i];
  {
    const float4* g4=reinterpret_cast<const float4*>(act+(size_t)b*IN_LEN);
    float4* s4=reinterpret_cast<float4*>(s_act);
    for (int i=threadIdx.x; i<432; i+=192) s4[i]=g4[i];
  }
  __syncthreads();
  int t=ts/24, s=ts-24*t;
  const int a1=24*L1*L1+t*N1, a2=24*L2*L2+s*N2;
  float f1r[N1],f1i[N1],f2r[N2],f2i[N2];
  #pragma unroll
  for (int x=0;x<N1;++x){ float2 v=s_act[a1+x]; f1r[x]=v.x; f1i[x]=v.y; }
  #pragma unroll
  for (int y=0;y<N2;++y){ float2 v=s_act[a2+y]; f2r[y]=v.x; f2i[y]=v.y; }
  float ss=0.f;
  size_t rowb=(size_t)mp.bb[TRI]+(size_t)brel*NM*KL+2*ts;
  #pragma unroll
  for (int m=0;m<NM;++m){
    float fr=0.f, fi=0.f;
    #pragma unroll
    for (int x=0;x<N1;++x){
      const int y=m-x+D;
      if (y>=0 && y<N2){
        float cv=cgl[m*N1+x];
        fr += cv*(f1r[x]*f2r[y]-f1i[x]*f2i[y]);
        fi += cv*(f1r[x]*f2i[y]+f1i[x]*f2r[y]);
      }
    }
    ss += fr*fr+fi*fi;
    union { bf16 h[2]; unsigned u; } pk;
    pk.h[0]=__float2bfloat16(fr); pk.h[1]=__float2bfloat16(fi);
    *reinterpret_cast<unsigned*>(Bm+rowb+(size_t)m*KL)=pk.u;
  }
  partial[(size_t)b*MS_LEN + mp.gch[TRI] + ts] = ss;
}

__global__ __launch_bounds__(192,4)
void k_mid3(const float2* __restrict__ act, const float* __restrict__ cg,
            bf16* __restrict__ Bm, float* __restrict__ partial, MPar mp, int b0){
  __shared__ float cgl[121];
  __shared__ float2 s_act[IN_LEN];
  int bx=blockIdx.x;
  int tri = mp.otri[bx/3], seg = bx - (bx/3)*3;
  int ts = seg*192 + threadIdx.x;
  #define CASE(T) case T: mid_body<T>(act,cg,Bm,partial,mp,ts,b0,cgl,s_act); break;
  switch(tri){
    CASE(0) CASE(1) CASE(2) CASE(3) CASE(4) CASE(5) CASE(6) CASE(7) CASE(8)
    CASE(9) CASE(10) CASE(11) CASE(12) CASE(13) CASE(14) CASE(15) CASE(16)
    CASE(17) CASE(18) CASE(19) CASE(20) CASE(21) CASE(22) CASE(23) CASE(24)
    CASE(25) CASE(26) CASE(27) CASE(28) CASE(29) CASE(30) CASE(31) CASE(32)
    CASE(33) CASE(34) CASE(35) CASE(36) CASE(37) CASE(38) CASE(39) CASE(40)
    CASE(41) CASE(42) CASE(43) CASE(44) CASE(45) CASE(46) CASE(47) CASE(48)
    CASE(49) CASE(50) CASE(51) CASE(52) CASE(53) CASE(54) CASE(55) CASE(56)
    CASE(57) CASE(58) CASE(59) CASE(60) CASE(61) CASE(62) CASE(63) CASE(64)
    CASE(65) CASE(66) CASE(67) CASE(68)
    default: break;
  }
  #undef CASE
}

// fused: per-channel scale computation + scaled stacked-real A build
__global__ __launch_bounds__(256)
void k_scaleA(const float* __restrict__ partial, const float* __restrict__ mstd,
              const float2* __restrict__ wts, bf16* __restrict__ Am, GMeta gm){
  int c=blockIdx.x*256+threadIdx.x;
  if (c>=MS_LEN) return;
  int l=0;
  #pragma unroll
  for (int i=1;i<6;++i) if (c>=gm.ms_off[i]) l=i;
  float ss=0.f;
  for (int g=0;g<NB;++g) ss += partial[(size_t)g*MS_LEN+c];
  float bstd = sqrtf(ss/(128.f*(float)(2*l+1)));
  float s = 1.f/(0.5f*(mstd[c]+bstd)+EPSV);
  int mt=gm.mt[l];
  int cl=c-gm.ms_off[l];
  size_t K=(size_t)gm.K[l];
  bf16* Al=Am+gm.aoff[l];
  const float2* Wl=wts+gm.w_off[l];
  #pragma unroll 4
  for (int o=0;o<24;++o){
    float2 w=Wl[(size_t)o*mt+cl];
    union { bf16 h[2]; unsigned u; } p0, p1;
    p0.h[0]=__float2bfloat16(w.x*s);  p0.h[1]=__float2bfloat16(-w.y*s);
    p1.h[0]=__float2bfloat16(w.y*s);  p1.h[1]=__float2bfloat16(w.x*s);
    *reinterpret_cast<unsigned*>(Al+(size_t)o*K+2*cl)      = p0.u;
    *reinterpret_cast<unsigned*>(Al+(size_t)(24+o)*K+2*cl) = p1.u;
  }
}

// GEMM with K split over blockIdx.y into 4 chunks; per-chunk 48x16 tile -> part
__global__ __launch_bounds__(256)
void k_gemm2(const bf16* __restrict__ Am, const bf16* __restrict__ Bm,
             float* __restrict__ part, GMeta gm){
  int bid=blockIdx.x, z=blockIdx.y;
  int l=0;
  #pragma unroll
  for (int i=1;i<6;++i) if (bid>=gm.tb[i]) l=i;
  int ntile=bid-gm.tb[l];
  int K=gm.K[l];
  int tid=threadIdx.x, lane=tid&63, w=tid>>6;
  int r=lane&15, kg=lane>>4;
  int nit=K>>7;
  int nz=(nit+3)>>2;
  int it0=z*nz, it1=(nit<it0+nz)?nit:(it0+nz);
  f32x4 acc0={0.f,0.f,0.f,0.f}, acc1=acc0, acc2=acc0;
  __shared__ float red[3072];
  if (it0<it1){
    const bf16* Al=Am+gm.aoff[l];
    const bf16* Bl=Bm+gm.boff[l];
    size_t koff=(size_t)(w*32+kg*8)+(size_t)it0*128;
    const short8* pa0=(const short8*)(Al+(size_t)r*K+koff);
    const short8* pa1=(const short8*)(Al+(size_t)(16+r)*K+koff);
    const short8* pa2=(const short8*)(Al+(size_t)(32+r)*K+koff);
    const short8* pb =(const short8*)(Bl+(size_t)(ntile*16+r)*K+koff);
    short8 ca0=*pa0, ca1=*pa1, ca2=*pa2, cb=*pb;
    for (int it=it0+1; it<it1; ++it){
      pa0+=16; pa1+=16; pa2+=16; pb+=16;
      short8 na0=*pa0, na1=*pa1, na2=*pa2, nb_=*pb;
      acc0=__builtin_amdgcn_mfma_f32_16x16x32_bf16(ca0,cb,acc0,0,0,0);
      acc1=__builtin_amdgcn_mfma_f32_16x16x32_bf16(ca1,cb,acc1,0,0,0);
      acc2=__builtin_amdgcn_mfma_f32_16x16x32_bf16(ca2,cb,acc2,0,0,0);
      ca0=na0; ca1=na1; ca2=na2; cb=nb_;
    }
    acc0=__builtin_amdgcn_mfma_f32_16x16x32_bf16(ca0,cb,acc0,0,0,0);
    acc1=__builtin_amdgcn_mfma_f32_16x16x32_bf16(ca1,cb,acc1,0,0,0);
    acc2=__builtin_amdgcn_mfma_f32_16x16x32_bf16(ca2,cb,acc2,0,0,0);
  }
  #pragma unroll
  for (int reg=0;reg<4;++reg){
    int row0=kg*4+reg;
    red[(w*48+row0)*16+r]     =acc0[reg];
    red[(w*48+16+row0)*16+r]  =acc1[reg];
    red[(w*48+32+row0)*16+r]  =acc2[reg];
  }
  __syncthreads();
  float* po = part + (size_t)(bid*4+z)*768;
  for (int e=tid;e<768;e+=256)
    po[e]=red[e]+red[768+e]+red[1536+e]+red[2304+e];
}

__global__ __launch_bounds__(256)
void k_red(const float* __restrict__ part, float* __restrict__ outf,
           GMeta gm, int b0){
  int bid=blockIdx.x;
  int l=0;
  #pragma unroll
  for (int i=1;i<6;++i) if (bid>=gm.tb[i]) l=i;
  int ntile=bid-gm.tb[l];
  int nm=2*l+1;
  const float* po = part + (size_t)bid*4*768;
  for (int e=threadIdx.x;e<768;e+=256){
    float sv=po[e]+po[768+e]+po[1536+e]+po[2304+e];
    int o=e>>4, cc=e&15;
    int n=ntile*16+cc;
    int bb=n/nm, m=n-bb*nm;
    int b=b0+bb;
    int oo=(o<24)?o:(o-24);
    int comp=(o<24)?0:1;
    outf[((size_t)b*IN_LEN + 24*l*l + oo*nm + m)*2 + comp]=sv;
  }
}

extern "C" void kernel_launch(void* const* d_in, const int* in_sizes, int n_in,
                              void* d_out, int out_size, void* d_ws, size_t ws_size,
                              hipStream_t stream) {
  const float2* act  = (const float2*)d_in[0];
  const float2* wts  = (const float2*)d_in[1];
  const float*  mstd = (const float*)d_in[2];
  float* outf = (float*)d_out;
  (void)in_sizes; (void)n_in; (void)out_size;

  GMeta gm; CMeta cm; MPar mp;
  for (int l=0;l<6;++l){ gm.mt[l]=MT[l]; gm.K[l]=2*MT[l]; }
  for (int l=0;l<7;++l) gm.ms_off[l]=MSOFF[l];
  for (int l=0;l<6;++l) gm.w_off[l]=24*gm.ms_off[l];
  int atot=0;
  for (int l=0;l<6;++l){ gm.aoff[l]=atot; atot+=48*gm.K[l]; }
  for (int i=0;i<NTRI;++i){
    cm.l1[i]=(unsigned char)TB.l1[i]; cm.l2[i]=(unsigned char)TB.l2[i];
    cm.lo[i]=(unsigned char)TB.lo[i]; cm.cg_off[i]=TB.cgoff[i];
    mp.gch[i]=MSOFF[TB.lo[i]]+TB.tpos[i]*576;
  }
  int ncg=TB.ncg;

  // heavy-first block order
  {
    int ordt[NTRI];
    for (int i=0;i<NTRI;++i) ordt[i]=i;
    for (int i=1;i<NTRI;++i){
      int v=ordt[i];
      int wv=(2*TB.lo[v]+1)*(2*TB.l1[v]+1);
      int j=i-1;
      while (j>=0){
        int wj=(2*TB.lo[ordt[j]]+1)*(2*TB.l1[ordt[j]]+1);
        if (wj>=wv) break;
        ordt[j+1]=ordt[j]; --j;
      }
      ordt[j+1]=v;
    }
    for (int i=0;i<NTRI;++i) mp.otri[i]=(unsigned char)ordt[i];
  }

  // ---- ws layout ----
  size_t ob=0;
  auto alloc=[&](size_t bytes){ size_t o=ob; ob=(ob+bytes+255)&~255ULL; return o; };
  size_t off_cg      = alloc((size_t)ncg*4);
  size_t off_partial = alloc((size_t)NB*MS_LEN*4);
  size_t off_A       = alloc((size_t)atot*2);
  size_t off_part    = alloc((size_t)288*4*768*4);
  size_t off_B       = ob;

  size_t perB=0;
  for (int l=0;l<6;++l) perB += (size_t)(2*l+1)*gm.K[l]*2;
  int nb=16;
  for (int cand : {128,64,32,16})
    if (off_B + (size_t)cand*perB <= ws_size){ nb=cand; break; }

  { int bo=0; for (int l=0;l<6;++l){ gm.boff[l]=bo; bo+=nb*(2*l+1)*gm.K[l]; } }
  gm.tb[0]=0;
  for (int l=0;l<6;++l) gm.tb[l+1]=gm.tb[l]+nb*(2*l+1)/16;
  for (int i=0;i<NTRI;++i)
    mp.bb[i] = gm.boff[TB.lo[i]] + TB.tpos[i]*1152;   // column base, interleaved K

  uint8_t* wsb=(uint8_t*)d_ws;
  float* cg      =(float*)(wsb+off_cg);
  float* partial =(float*)(wsb+off_partial);
  bf16*  Am      =(bf16*)(wsb+off_A);
  float* part    =(float*)(wsb+off_part);
  bf16*  Bm      =(bf16*)(wsb+off_B);

  k_init_cg<<<NTRI,64,0,stream>>>(cg, cm);
  int tiles=gm.tb[6];
  if (nb==NB){
    k_mid3<<<dim3(NTRI*3,NB),192,0,stream>>>(act,cg,Bm,partial,mp,0);
    k_scaleA<<<(MS_LEN+255)/256,256,0,stream>>>(partial,mstd,wts,Am,gm);
    k_gemm2<<<dim3(tiles,4),256,0,stream>>>(Am,Bm,part,gm);
    k_red<<<tiles,256,0,stream>>>(part,outf,gm,0);
  } else {
    for (int b0=0;b0<NB;b0+=nb)
      k_mid3<<<dim3(NTRI*3,nb),192,0,stream>>>(act,cg,Bm,partial,mp,b0);
    k_scaleA<<<(MS_LEN+255)/256,256,0,stream>>>(partial,mstd,wts,Am,gm);
    for (int b0=0;b0<NB;b0+=nb){
      k_mid3<<<dim3(NTRI*3,nb),192,0,stream>>>(act,cg,Bm,partial,mp,b0);
      k_gemm2<<<dim3(tiles,4),256,0,stream>>>(Am,Bm,part,gm);
      k_red<<<tiles,256,0,stream>>>(part,outf,gm,b0);
    }
  }
}